// Round 14
// baseline (898.915 us; speedup 1.0000x reference)
//
#include <hip/hip_runtime.h>

// ---- problem constants -------------------------------------------------
#define Bn 2
#define Sn 2048
#define Hn 3584
#define NHn 28
#define NKVn 4
#define HDn 128
#define GROUPSn 7
#define SCALEF 0.08838834764831845f
#define NOUT 14680064LL /* B*S*H */

typedef __attribute__((ext_vector_type(4))) float f4v;
typedef __attribute__((ext_vector_type(16))) float f32x16;
typedef __attribute__((ext_vector_type(8))) short bf16x8;
typedef __attribute__((ext_vector_type(4))) short s16x4;

typedef __attribute__((address_space(1))) void gvoid;
typedef __attribute__((address_space(3))) void lvoid;
#define GLL16(g, l) __builtin_amdgcn_global_load_lds((gvoid*)(void*)(g), (lvoid*)(l), 16, 0, 0)

__device__ __forceinline__ short f2bf(float f) {
  unsigned u = __builtin_bit_cast(unsigned, f);
  u = (u + 0x7fffu + ((u >> 16) & 1u)) >> 16;  // RTNE
  return (short)u;
}

// ---- cast / small prep kernels ----------------------------------------
__global__ __launch_bounds__(256) void cast_bf16(const float* __restrict__ in,
                                                 short* __restrict__ out, long long n4) {
  long long i = (long long)blockIdx.x * 256 + threadIdx.x;
  long long stride = (long long)gridDim.x * 256;
  for (; i < n4; i += stride) {
    f4v f = ((const f4v*)in)[i];
    s16x4 o = { f2bf(f.x), f2bf(f.y), f2bf(f.z), f2bf(f.w) };
    ((s16x4*)out)[i] = o;
  }
}

__global__ __launch_bounds__(256) void concat_bias(const float* __restrict__ bq,
                                                   const float* __restrict__ bk,
                                                   const float* __restrict__ bv,
                                                   float* __restrict__ out) {
  int i = blockIdx.x * 256 + threadIdx.x;
  if (i < 3584) out[i] = bq[i];
  else if (i < 4096) out[i] = bk[i - 3584];
  else if (i < 4608) out[i] = bv[i - 4096];
}

// ---- shared 128x128 bf16 MFMA GEMM core (m97 structure, BK=32) --------
__device__ __forceinline__ void mm128_core(const short* __restrict__ Atile, long long lda,
                                           const short* __restrict__ Btile, long long ldb,
                                           int nk, short* lA, short* lB, f4v (&acc)[4][4]) {
  const int tid = threadIdx.x;
  const int lane = tid & 63;
  const int wr = (tid >> 6) >> 1, wc = (tid >> 6) & 1;
  const int srow = tid >> 2;
  const int scol = (tid & 3) * 8;
  const short* a0 = Atile + (long long)srow * lda + scol;
  const short* a1 = Atile + (long long)(srow + 64) * lda + scol;
  const short* b0 = Btile + (long long)srow * ldb + scol;
  const short* b1 = Btile + (long long)(srow + 64) * ldb + scol;
  short* la0 = lA + tid * 8;
  short* la1 = lA + (256 + tid) * 8;
  short* lb0 = lB + tid * 8;
  short* lb1 = lB + (256 + tid) * 8;
  const int fr = lane & 15;
  const int kc = (lane >> 4) * 8;
  for (int kt = 0; kt < nk; ++kt) {
    GLL16(a0 + kt * 32, la0);
    GLL16(a1 + kt * 32, la1);
    GLL16(b0 + kt * 32, lb0);
    GLL16(b1 + kt * 32, lb1);
    __syncthreads();
    bf16x8 af[4], bf[4];
#pragma unroll
    for (int m = 0; m < 4; ++m)
      af[m] = *(const bf16x8*)&lA[(wr * 64 + m * 16 + fr) * 32 + kc];
#pragma unroll
    for (int n = 0; n < 4; ++n)
      bf[n] = *(const bf16x8*)&lB[(wc * 64 + n * 16 + fr) * 32 + kc];
#pragma unroll
    for (int m = 0; m < 4; ++m)
#pragma unroll
      for (int n = 0; n < 4; ++n)
        acc[m][n] = __builtin_amdgcn_mfma_f32_16x16x32_bf16(af[m], bf[n], acc[m][n], 0, 0, 0);
    __syncthreads();
  }
}

// ---- persistent GEMM with optional bias, fp32 out ---------------------
// grid = 768 (256 CU x 3 blocks/CU); blocks grid-stride over tiles with
// XCD-chunked mapping: block p lands on XCD p%8; tile map (vt&7)*nt8+(vt>>3)
// gives XCD x the contiguous range [x*nt8,(x+1)*nt8) -> neighbor tiles
// share operand panels in that XCD's L2 (T1). Kills the half-empty tail
// round of the 1152/896-block launches.
__global__ __launch_bounds__(256) void gemm_persist(const short* __restrict__ A,
                                                    const short* __restrict__ B,
                                                    float* __restrict__ C,
                                                    const float* __restrict__ bias,
                                                    int K, int N, int gx, int ntiles) {
  __shared__ alignas(16) short lA[4096];
  __shared__ alignas(16) short lB[4096];
  const int nt8 = ntiles >> 3;                 // ntiles % 8 == 0 at both call sites
  const int lane = threadIdx.x & 63;
  const int wr = (threadIdx.x >> 6) >> 1, wc = (threadIdx.x >> 6) & 1;
  const int rr = (lane >> 4) * 4, cc = lane & 15;
  for (int vt = blockIdx.x; vt < ntiles; vt += gridDim.x) {
    const int tile = (vt & 7) * nt8 + (vt >> 3);
    const int bx = tile % gx, by = tile / gx;
    const long long brow = (long long)by * 128;
    const long long bcol = (long long)bx * 128;
    f4v acc[4][4] = {};
    mm128_core(A + brow * K, K, B + bcol * K, K, K >> 5, lA, lB, acc);
#pragma unroll
    for (int n = 0; n < 4; ++n) {
      long long col = bcol + wc * 64 + n * 16 + cc;
      float bv = bias ? bias[col] : 0.f;
#pragma unroll
      for (int m = 0; m < 4; ++m) {
#pragma unroll
        for (int j = 0; j < 4; ++j) {
          long long row = brow + wr * 64 + m * 16 + rr + j;
          C[row * N + col] = acc[m][n][j] + bv;
        }
      }
    }
  }
}

// ---- RoPE on q,k (reads fp32 qkv, writes bf16 (b,h,s,d)) --------------
__global__ __launch_bounds__(256) void rope_qk(const float* __restrict__ qkv,
                                               const float* __restrict__ cosb,
                                               const float* __restrict__ sinb,
                                               short* __restrict__ qo,
                                               short* __restrict__ ko) {
  long long bs = blockIdx.x;              // 0..B*S-1
  int b = (int)(bs >> 11);
  int s = (int)(bs & 2047);
  const float* row = qkv + bs * 4608;
  const float* cp = cosb + bs * 128;
  const float* sp = sinb + bs * 128;
  for (int i = threadIdx.x; i < 4096; i += 256) {
    int d = i & 127;
    float c = cp[d], sn = sp[d];
    float x = row[i];
    float xr = (d < 64) ? -row[i + 64] : row[i - 64];
    short v = f2bf(x * c + xr * sn);
    if (i < 3584) {
      int h = i >> 7;
      qo[(((long long)(b * NHn + h) * Sn + s)) * HDn + d] = v;
    } else {
      int h = (i - 3584) >> 7;
      ko[(((long long)(b * NKVn + h) * Sn + s)) * HDn + d] = v;
    }
  }
}

// ---- v transpose: qkv fp32 v-section (b,s,kv,d) -> vT bf16 (b,kv,d,s) -
__global__ void vtrans(const float* __restrict__ qkv, short* __restrict__ vt) {
  __shared__ float tile[32][33];
  int bh = blockIdx.z;                    // b*NKV+kv
  int b = bh >> 2, h = bh & 3;
  int s0 = blockIdx.x * 32, d0 = blockIdx.y * 32;
  int tx = threadIdx.x, ty = threadIdx.y;  // 32 x 8
#pragma unroll
  for (int j = 0; j < 32; j += 8) {
    int s = s0 + ty + j;
    tile[ty + j][tx] = qkv[((long long)(b * Sn + s)) * 4608 + 4096 + h * 128 + d0 + tx];
  }
  __syncthreads();
#pragma unroll
  for (int j = 0; j < 32; j += 8) {
    int d = d0 + ty + j;
    vt[((long long)(bh * 128 + d)) * Sn + s0 + tx] = f2bf(tile[tx][ty + j]);
  }
}

// ---- fused attention v5: v4 + hoisted P stores ------------------------
// v4 (validated 893-total) with one change: BOTH a-values' pn computed and
// all 8 P stores issued immediately after barrier B, BEFORE any PV MFMA.
// Last-store -> barrier-A distance grows ~400cy -> ~800+cy so L2 store
// acks fully hide under the PV chains. (+~20 VGPR; occupancy watch-item.)
__global__ __launch_bounds__(256, 1) void fused_attn5(const short* __restrict__ Q,
                                                      const short* __restrict__ Kb,
                                                      const short* __restrict__ Vt,
                                                      float* __restrict__ probs,
                                                      short* __restrict__ attn) {
  __shared__ alignas(16) short lK[2][8192];    // 2 x 16 KB K tiles (64x128)
  __shared__ alignas(16) short lV[8192];       // 16 KB V tile (128d x 64k)
  const int tid = threadIdx.x;
  const int w = tid >> 6;
  const int lane = tid & 63;
  const int lam = lane & 31, h = lane >> 5;
  const int qb = 15 - (int)blockIdx.x;         // heavy blocks first
  const int bh = blockIdx.y;
  const int b = bh / NHn, hh = bh - b * NHn, kv = hh / GROUPSn;
  const short* Qb = Q + (long long)bh * (Sn * HDn);
  const short* Kbb = Kb + (long long)(b * NKVn + kv) * (Sn * HDn);
  const short* Vb = Vt + (long long)(b * NKVn + kv) * (HDn * Sn);
  float* Pb = probs + (long long)bh * ((long long)Sn * Sn) + (long long)qb * 128 * Sn;
  const int qloc = w * 32 + lam;               // this lane's q row (0..127)

  // Q as B-frag (32x32x16): lane holds Q[q=qloc][d = s*16 + h*8 + 0..7]
  bf16x8 qf[8];
  {
    const short* qr = Qb + (long long)(qb * 128 + qloc) * HDn + h * 8;
#pragma unroll
    for (int s = 0; s < 8; ++s) qf[s] = *(const bf16x8*)(qr + s * 16);
  }
  // K staging map (64x128 tile, 16 chunks/row): chunk M -> row M>>4,
  // src chunk (M&15)^(row&15)
  int rswK[4], cswK[4];
#pragma unroll
  for (int i = 0; i < 4; ++i) {
    int M = i * 256 + tid;
    rswK[i] = M >> 4;
    cswK[i] = (M & 15) ^ (rswK[i] & 15);
  }
  // V staging map (128x64 tile, 8 chunks/row): chunk M -> row M>>3,
  // src chunk (M&7)^(row&7)
  int rswV[4], cswV[4];
#pragma unroll
  for (int i = 0; i < 4; ++i) {
    int M = i * 256 + tid;
    rswV[i] = M >> 3;
    cswV[i] = (M & 7) ^ (rswV[i] & 7);
  }
  const int c8 = lam & 15;                     // K read-side xor
  const int v8 = lam & 7;                      // V read-side xor
  const int nkt = 2 * qb + 2;                  // 64-row K tiles

#define STAGEK(BUF, KT) do {                                                      \
    const short* base_ = Kbb + (long long)(KT) * 64 * HDn;                        \
    _Pragma("unroll")                                                             \
    for (int i = 0; i < 4; ++i)                                                   \
      GLL16(base_ + (long long)rswK[i] * HDn + cswK[i] * 8,                       \
            (short*)lK[BUF] + (i * 256 + tid) * 8);                               \
  } while (0)

#define STAGEV(KT) do {                                                           \
    _Pragma("unroll")                                                             \
    for (int i = 0; i < 4; ++i)                                                   \
      GLL16(Vb + (long long)rswV[i] * Sn + (KT) * 64 + cswV[i] * 8,               \
            lV + (i * 256 + tid) * 8);                                            \
  } while (0)

  // QK^T for one 64-tile: K as A-frag, lane holds K[k=a*32+lam][d-slice]
#define QKT2(ACCP, LCUR) do {                                                     \
    _Pragma("unroll")                                                             \
    for (int s = 0; s < 8; ++s) {                                                 \
      const int co_ = ((s * 2 + h) ^ c8) * 8;                                     \
      _Pragma("unroll")                                                           \
      for (int a = 0; a < 2; ++a) {                                               \
        bf16x8 kf_ = *(const bf16x8*)&(LCUR)[(a * 32 + lam) * 128 + co_];         \
        ACCP[a] = __builtin_amdgcn_mfma_f32_32x32x16_bf16(kf_, qf[s], ACCP[a], 0, 0, 0); \
      }                                                                           \
    }                                                                             \
  } while (0)

  // -------- pass 1: row sums only --------
  float lsum = 0.f;
  STAGEK(0, 0);
  int cur = 0;
  for (int kt = 0; kt < nkt; ++kt) {
    __syncthreads();
    if (kt + 1 < nkt) STAGEK(cur ^ 1, kt + 1);
    const short* lcur = (const short*)lK[cur];
    f32x16 accp[2] = {};
    QKT2(accp, lcur);
    const int kbase = kt * 64 - qb * 128;      // mask: kbase+kloc > qloc -> 0
#pragma unroll
    for (int a = 0; a < 2; ++a)
#pragma unroll
      for (int r = 0; r < 16; ++r) {
        int kloc = a * 32 + (r & 3) + 8 * (r >> 2) + 4 * h;
        float s = fminf(accp[a][r] * SCALEF, 60.f);
        float p = __expf(s);
        if (kbase + kloc > qloc) p = 0.f;
        lsum += p;
      }
    cur ^= 1;
  }
  lsum += __shfl_xor(lsum, 32);                // lanes l, l^32 share q
  const float invl = 1.f / lsum;

  // -------- pass 2: normalized P write + PV from LDS V --------
  __syncthreads();                             // all pass-1 lK reads done
  STAGEK(0, 0);
  cur = 0;
  f32x16 acco[4] = {};
  for (int kt = 0; kt < nkt; ++kt) {
    __syncthreads();                           // A: K[kt] ready, lV free
    if (kt + 1 < nkt) STAGEK(cur ^ 1, kt + 1);
    STAGEV(kt);
    const short* lcur = (const short*)lK[cur];
    f32x16 accp[2] = {};
    QKT2(accp, lcur);
    __syncthreads();                           // B: V[kt] landed
    const int kbase = kt * 64 - qb * 128;
    float* prow = Pb + (long long)qloc * Sn + kt * 64 + 4 * h;
    // --- hoisted: compute both a's pn + issue ALL P stores first ---
    float pn2[2][16];
#pragma unroll
    for (int a = 0; a < 2; ++a) {
#pragma unroll
      for (int r = 0; r < 16; ++r) {
        int kloc = a * 32 + (r & 3) + 8 * (r >> 2) + 4 * h;
        float s = fminf(accp[a][r] * SCALEF, 60.f);
        float p = __expf(s) * invl;
        if (kbase + kloc > qloc) p = 0.f;
        pn2[a][r] = p;
      }
#pragma unroll
      for (int T = 0; T < 4; ++T) {
        f4v v = { pn2[a][4 * T], pn2[a][4 * T + 1], pn2[a][4 * T + 2], pn2[a][4 * T + 3] };
        *(f4v*)(prow + a * 32 + 8 * T) = v;
      }
    }
    // --- PV for both a's (stores ack under these ~16 MFMA chains) ---
#pragma unroll
    for (int a = 0; a < 2; ++a) {
#pragma unroll
      for (int ci = 0; ci < 2; ++ci) {
        const int ro = ci * 8;
        float r0 = __shfl_xor(h ? pn2[a][ro + 0] : pn2[a][ro + 4], 32);
        float r1 = __shfl_xor(h ? pn2[a][ro + 1] : pn2[a][ro + 5], 32);
        float r2 = __shfl_xor(h ? pn2[a][ro + 2] : pn2[a][ro + 6], 32);
        float r3 = __shfl_xor(h ? pn2[a][ro + 3] : pn2[a][ro + 7], 32);
        float t0 = h ? r0 : pn2[a][ro + 0];
        float t1 = h ? r1 : pn2[a][ro + 1];
        float t2 = h ? r2 : pn2[a][ro + 2];
        float t3 = h ? r3 : pn2[a][ro + 3];
        float t4 = h ? pn2[a][ro + 4] : r0;
        float t5 = h ? pn2[a][ro + 5] : r1;
        float t6 = h ? pn2[a][ro + 6] : r2;
        float t7 = h ? pn2[a][ro + 7] : r3;
        bf16x8 pf = { f2bf(t0), f2bf(t1), f2bf(t2), f2bf(t3),
                      f2bf(t4), f2bf(t5), f2bf(t6), f2bf(t7) };
        const int c = a * 2 + ci;
#pragma unroll
        for (int f = 0; f < 4; ++f) {
          bf16x8 vf = *(const bf16x8*)&lV[(f * 32 + lam) * 64 + ((c * 2 + h) ^ v8) * 8];
          acco[f] = __builtin_amdgcn_mfma_f32_32x32x16_bf16(pf, vf, acco[f], 0, 0, 0);
        }
      }
    }
    cur ^= 1;
  }
#undef QKT2
#undef STAGEV
#undef STAGEK

  // attn epilogue: O[q = w*32 + (r&3)+8(r>>2)+4h][d = f*32+lam], normalized
#pragma unroll
  for (int f = 0; f < 4; ++f)
#pragma unroll
    for (int r = 0; r < 16; ++r) {
      int qv = (r & 3) + 8 * (r >> 2) + 4 * h;
      long long q = (long long)qb * 128 + w * 32 + qv;
      attn[((long long)(b * Sn) + q) * Hn + hh * HDn + f * 32 + lam] = f2bf(acco[f][r]);
    }

  // inline upper-triangle zeros for this block's 128 rows
  {
    const int r0 = tid >> 3;
    const int c0 = tid & 7;
    f4v z = {0.f, 0.f, 0.f, 0.f};
    for (int ct = qb + 1; ct < 16; ++ct) {
      float* base = Pb + (long long)ct * 128;
#pragma unroll
      for (int rr = 0; rr < 128; rr += 32) {
        f4v* rowp = (f4v*)(base + (long long)(r0 + rr) * Sn);
#pragma unroll
        for (int c = 0; c < 4; ++c) __builtin_nontemporal_store(z, &rowp[c0 + c * 8]);
      }
    }
  }
}

// ---- workspace layout (bytes) -----------------------------------------
// hs_bf16   @ 0          (29,360,128)  -- reused later as attn_bf16
// wqkv_bf16 @ 29,360,128 (33,030,144)  -- reused later as q_bf16
// wo_bf16   @ 62,390,272 (25,690,112)
// bias_qkv  @ 88,080,384 (18,432)
// qkv_f32   @ 88,098,816 (75,497,472)
// k_bf16    @163,596,288 ( 4,194,304)
// vT_bf16   @167,790,592 ( 4,194,304)   total = 171,984,896 B

extern "C" void kernel_launch(void* const* d_in, const int* in_sizes, int n_in,
                              void* d_out, int out_size, void* d_ws, size_t ws_size,
                              hipStream_t stream) {
  const float* hs   = (const float*)d_in[0];
  const float* cosb = (const float*)d_in[1];
  const float* sinb = (const float*)d_in[2];
  // d_in[3] attention_mask: exact causal tril 0/-1e9, applied analytically
  const float* Wq = (const float*)d_in[4];
  const float* bq = (const float*)d_in[5];
  const float* Wk = (const float*)d_in[6];
  const float* bk = (const float*)d_in[7];
  const float* Wv = (const float*)d_in[8];
  const float* bv = (const float*)d_in[9];
  const float* Wo = (const float*)d_in[10];
  float* out   = (float*)d_out;
  float* probs = out + NOUT;
  char* ws = (char*)d_ws;
  short* hs_bf   = (short*)(ws + 0);
  short* attn_bf = hs_bf;                      // alias: hs dead after QKV GEMM
  short* wqkv_bf = (short*)(ws + 29360128LL);
  short* q_bf    = wqkv_bf;                    // alias: wqkv dead after QKV GEMM
  short* wo_bf   = (short*)(ws + 62390272LL);
  float* bias_qkv= (float*)(ws + 88080384LL);
  float* qkv     = (float*)(ws + 88098816LL);
  short* k_bf    = (short*)(ws + 163596288LL);
  short* vt_bf   = (short*)(ws + 167790592LL);

  cast_bf16<<<2048, 256, 0, stream>>>(hs, hs_bf, 3670016LL);
  cast_bf16<<<2048, 256, 0, stream>>>(Wq, wqkv_bf, 3211264LL);
  cast_bf16<<<512, 256, 0, stream>>>(Wk, wqkv_bf + 12845056LL, 458752LL);
  cast_bf16<<<512, 256, 0, stream>>>(Wv, wqkv_bf + 14680064LL, 458752LL);
  cast_bf16<<<2048, 256, 0, stream>>>(Wo, wo_bf, 3211264LL);
  concat_bias<<<18, 256, 0, stream>>>(bq, bk, bv, bias_qkv);

  // fused QKV projection: persistent grid (768 = 256 CU x 3 blk/CU)
  gemm_persist<<<768, 256, 0, stream>>>(hs_bf, wqkv_bf, qkv, bias_qkv, 3584, 4608, 36, 1152);

  rope_qk<<<4096, 256, 0, stream>>>(qkv, cosb, sinb, q_bf, k_bf);
  vtrans<<<dim3(64, 4, 8), dim3(32, 8), 0, stream>>>(qkv, vt_bf);

  // fully-fused attention (normalized P + attn + inline upper zeros)
  fused_attn5<<<dim3(16, 56), 256, 0, stream>>>(q_bf, k_bf, vt_bf, probs, attn_bf);

  // out = attn @ Wo^T: persistent grid
  gemm_persist<<<768, 256, 0, stream>>>(attn_bf, wo_bf, out, nullptr, 3584, 3584, 28, 896);
}

// Round 15
// 870.345 us; speedup vs baseline: 1.0328x; 1.0328x over previous
//
#include <hip/hip_runtime.h>

// ---- problem constants -------------------------------------------------
#define Bn 2
#define Sn 2048
#define Hn 3584
#define NHn 28
#define NKVn 4
#define HDn 128
#define GROUPSn 7
#define SCALEF 0.08838834764831845f
#define NOUT 14680064LL /* B*S*H */

typedef __attribute__((ext_vector_type(4))) float f4v;
typedef __attribute__((ext_vector_type(16))) float f32x16;
typedef __attribute__((ext_vector_type(8))) short bf16x8;
typedef __attribute__((ext_vector_type(4))) short s16x4;

typedef __attribute__((address_space(1))) void gvoid;
typedef __attribute__((address_space(3))) void lvoid;
#define GLL16(g, l) __builtin_amdgcn_global_load_lds((gvoid*)(void*)(g), (lvoid*)(l), 16, 0, 0)

__device__ __forceinline__ short f2bf(float f) {
  unsigned u = __builtin_bit_cast(unsigned, f);
  u = (u + 0x7fffu + ((u >> 16) & 1u)) >> 16;  // RTNE
  return (short)u;
}

// ---- cast / small prep kernels ----------------------------------------
__global__ __launch_bounds__(256) void cast_bf16(const float* __restrict__ in,
                                                 short* __restrict__ out, long long n4) {
  long long i = (long long)blockIdx.x * 256 + threadIdx.x;
  long long stride = (long long)gridDim.x * 256;
  for (; i < n4; i += stride) {
    f4v f = ((const f4v*)in)[i];
    s16x4 o = { f2bf(f.x), f2bf(f.y), f2bf(f.z), f2bf(f.w) };
    ((s16x4*)out)[i] = o;
  }
}

__global__ __launch_bounds__(256) void concat_bias(const float* __restrict__ bq,
                                                   const float* __restrict__ bk,
                                                   const float* __restrict__ bv,
                                                   float* __restrict__ out) {
  int i = blockIdx.x * 256 + threadIdx.x;
  if (i < 3584) out[i] = bq[i];
  else if (i < 4096) out[i] = bk[i - 3584];
  else if (i < 4608) out[i] = bv[i - 4096];
}

// ---- 128x128 bf16 MFMA GEMM core, BK=64, XOR-swizzled LDS -------------
// vs m97/BK=32: half the barriers (nk=K/64), 32 MFMA per barrier. Row
// stride 128B would be a 16-way bank conflict -> same chunk^(row&7)
// swizzle as the attention K staging (rule #21: linear LDS dst +
// inverse-swizzled global src + swizzled read; residual 2-way = free).
__device__ __forceinline__ void mm128x64_core(const short* __restrict__ Atile, long long lda,
                                              const short* __restrict__ Btile, long long ldb,
                                              int nk, short* lA, short* lB, f4v (&acc)[4][4]) {
  const int tid = threadIdx.x;
  const int lane = tid & 63;
  const int wr = (tid >> 6) >> 1, wc = (tid >> 6) & 1;
  const int fr = lane & 15;
  const int g = lane >> 4;
  int rsw[4], csw[4];
#pragma unroll
  for (int i = 0; i < 4; ++i) {
    int M = i * 256 + tid;                 // 1024 16B-chunks per 128x64 tile
    rsw[i] = M >> 3;                       // row (8 chunks/row)
    csw[i] = (M & 7) ^ (rsw[i] & 7);       // inverse-swizzled source chunk
  }
  for (int kt = 0; kt < nk; ++kt) {
#pragma unroll
    for (int i = 0; i < 4; ++i) {
      GLL16(Atile + (long long)rsw[i] * lda + kt * 64 + csw[i] * 8, lA + (i * 256 + tid) * 8);
      GLL16(Btile + (long long)rsw[i] * ldb + kt * 64 + csw[i] * 8, lB + (i * 256 + tid) * 8);
    }
    __syncthreads();
#pragma unroll
    for (int kk = 0; kk < 2; ++kk) {
      bf16x8 af[4], bf[4];
#pragma unroll
      for (int m = 0; m < 4; ++m) {
        int r = wr * 64 + m * 16 + fr;
        af[m] = *(const bf16x8*)&lA[r * 64 + ((kk * 4 + g) ^ (r & 7)) * 8];
      }
#pragma unroll
      for (int n = 0; n < 4; ++n) {
        int r = wc * 64 + n * 16 + fr;
        bf[n] = *(const bf16x8*)&lB[r * 64 + ((kk * 4 + g) ^ (r & 7)) * 8];
      }
#pragma unroll
      for (int m = 0; m < 4; ++m)
#pragma unroll
        for (int n = 0; n < 4; ++n)
          acc[m][n] = __builtin_amdgcn_mfma_f32_16x16x32_bf16(af[m], bf[n], acc[m][n], 0, 0, 0);
    }
    __syncthreads();
  }
}

// ---- persistent GEMM with optional bias, fp32 out ---------------------
__global__ __launch_bounds__(256) void gemm_persist(const short* __restrict__ A,
                                                    const short* __restrict__ B,
                                                    float* __restrict__ C,
                                                    const float* __restrict__ bias,
                                                    int K, int N, int gx, int ntiles) {
  __shared__ alignas(16) short lA[8192];       // 16 KB (128x64)
  __shared__ alignas(16) short lB[8192];       // 16 KB
  const int nt8 = ntiles >> 3;                 // ntiles % 8 == 0 at both call sites
  const int lane = threadIdx.x & 63;
  const int wr = (threadIdx.x >> 6) >> 1, wc = (threadIdx.x >> 6) & 1;
  const int rr = (lane >> 4) * 4, cc = lane & 15;
  for (int vt = blockIdx.x; vt < ntiles; vt += gridDim.x) {
    const int tile = (vt & 7) * nt8 + (vt >> 3);   // XCD-chunked tile map
    const int bx = tile % gx, by = tile / gx;
    const long long brow = (long long)by * 128;
    const long long bcol = (long long)bx * 128;
    f4v acc[4][4] = {};
    mm128x64_core(A + brow * K, K, B + bcol * K, K, K >> 6, lA, lB, acc);
#pragma unroll
    for (int n = 0; n < 4; ++n) {
      long long col = bcol + wc * 64 + n * 16 + cc;
      float bv = bias ? bias[col] : 0.f;
#pragma unroll
      for (int m = 0; m < 4; ++m) {
#pragma unroll
        for (int j = 0; j < 4; ++j) {
          long long row = brow + wr * 64 + m * 16 + rr + j;
          C[row * N + col] = acc[m][n][j] + bv;
        }
      }
    }
  }
}

// ---- RoPE on q,k (reads fp32 qkv, writes bf16 (b,h,s,d)) --------------
__global__ __launch_bounds__(256) void rope_qk(const float* __restrict__ qkv,
                                               const float* __restrict__ cosb,
                                               const float* __restrict__ sinb,
                                               short* __restrict__ qo,
                                               short* __restrict__ ko) {
  long long bs = blockIdx.x;              // 0..B*S-1
  int b = (int)(bs >> 11);
  int s = (int)(bs & 2047);
  const float* row = qkv + bs * 4608;
  const float* cp = cosb + bs * 128;
  const float* sp = sinb + bs * 128;
  for (int i = threadIdx.x; i < 4096; i += 256) {
    int d = i & 127;
    float c = cp[d], sn = sp[d];
    float x = row[i];
    float xr = (d < 64) ? -row[i + 64] : row[i - 64];
    short v = f2bf(x * c + xr * sn);
    if (i < 3584) {
      int h = i >> 7;
      qo[(((long long)(b * NHn + h) * Sn + s)) * HDn + d] = v;
    } else {
      int h = (i - 3584) >> 7;
      ko[(((long long)(b * NKVn + h) * Sn + s)) * HDn + d] = v;
    }
  }
}

// ---- v transpose: qkv fp32 v-section (b,s,kv,d) -> vT bf16 (b,kv,d,s) -
__global__ void vtrans(const float* __restrict__ qkv, short* __restrict__ vt) {
  __shared__ float tile[32][33];
  int bh = blockIdx.z;                    // b*NKV+kv
  int b = bh >> 2, h = bh & 3;
  int s0 = blockIdx.x * 32, d0 = blockIdx.y * 32;
  int tx = threadIdx.x, ty = threadIdx.y;  // 32 x 8
#pragma unroll
  for (int j = 0; j < 32; j += 8) {
    int s = s0 + ty + j;
    tile[ty + j][tx] = qkv[((long long)(b * Sn + s)) * 4608 + 4096 + h * 128 + d0 + tx];
  }
  __syncthreads();
#pragma unroll
  for (int j = 0; j < 32; j += 8) {
    int d = d0 + ty + j;
    vt[((long long)(bh * 128 + d)) * Sn + s0 + tx] = f2bf(tile[tx][ty + j]);
  }
}

// ---- fused attention v6: v4 + pass-2 barrier unburdening --------------
// v4 body (893-total validated) with ONE change: pass-2 issues STAGEV
// right after barrier A (drains at barrier B under QK^T's 32 MFMA) and
// STAGEK(next) AFTER barrier B (drains at next barrier A under the full
// pn/P-store/PV phase, ~1300cy) instead of before barrier B where its
// drain stalled barrier B. Buffer lifetimes unchanged (lV reads drain at
// A; lK[cur^1] readers come after the next A).
__global__ __launch_bounds__(256, 1) void fused_attn6(const short* __restrict__ Q,
                                                      const short* __restrict__ Kb,
                                                      const short* __restrict__ Vt,
                                                      float* __restrict__ probs,
                                                      short* __restrict__ attn) {
  __shared__ alignas(16) short lK[2][8192];    // 2 x 16 KB K tiles (64x128)
  __shared__ alignas(16) short lV[8192];       // 16 KB V tile (128d x 64k)
  const int tid = threadIdx.x;
  const int w = tid >> 6;
  const int lane = tid & 63;
  const int lam = lane & 31, h = lane >> 5;
  const int qb = 15 - (int)blockIdx.x;         // heavy blocks first
  const int bh = blockIdx.y;
  const int b = bh / NHn, hh = bh - b * NHn, kv = hh / GROUPSn;
  const short* Qb = Q + (long long)bh * (Sn * HDn);
  const short* Kbb = Kb + (long long)(b * NKVn + kv) * (Sn * HDn);
  const short* Vb = Vt + (long long)(b * NKVn + kv) * (HDn * Sn);
  float* Pb = probs + (long long)bh * ((long long)Sn * Sn) + (long long)qb * 128 * Sn;
  const int qloc = w * 32 + lam;               // this lane's q row (0..127)

  // Q as B-frag (32x32x16): lane holds Q[q=qloc][d = s*16 + h*8 + 0..7]
  bf16x8 qf[8];
  {
    const short* qr = Qb + (long long)(qb * 128 + qloc) * HDn + h * 8;
#pragma unroll
    for (int s = 0; s < 8; ++s) qf[s] = *(const bf16x8*)(qr + s * 16);
  }
  // K staging map (64x128 tile, 16 chunks/row): chunk M -> row M>>4,
  // src chunk (M&15)^(row&15)
  int rswK[4], cswK[4];
#pragma unroll
  for (int i = 0; i < 4; ++i) {
    int M = i * 256 + tid;
    rswK[i] = M >> 4;
    cswK[i] = (M & 15) ^ (rswK[i] & 15);
  }
  // V staging map (128x64 tile, 8 chunks/row): chunk M -> row M>>3,
  // src chunk (M&7)^(row&7)
  int rswV[4], cswV[4];
#pragma unroll
  for (int i = 0; i < 4; ++i) {
    int M = i * 256 + tid;
    rswV[i] = M >> 3;
    cswV[i] = (M & 7) ^ (rswV[i] & 7);
  }
  const int c8 = lam & 15;                     // K read-side xor
  const int v8 = lam & 7;                      // V read-side xor
  const int nkt = 2 * qb + 2;                  // 64-row K tiles

#define STAGEK(BUF, KT) do {                                                      \
    const short* base_ = Kbb + (long long)(KT) * 64 * HDn;                        \
    _Pragma("unroll")                                                             \
    for (int i = 0; i < 4; ++i)                                                   \
      GLL16(base_ + (long long)rswK[i] * HDn + cswK[i] * 8,                       \
            (short*)lK[BUF] + (i * 256 + tid) * 8);                               \
  } while (0)

#define STAGEV(KT) do {                                                           \
    _Pragma("unroll")                                                             \
    for (int i = 0; i < 4; ++i)                                                   \
      GLL16(Vb + (long long)rswV[i] * Sn + (KT) * 64 + cswV[i] * 8,               \
            lV + (i * 256 + tid) * 8);                                            \
  } while (0)

  // QK^T for one 64-tile: K as A-frag, lane holds K[k=a*32+lam][d-slice]
#define QKT2(ACCP, LCUR) do {                                                     \
    _Pragma("unroll")                                                             \
    for (int s = 0; s < 8; ++s) {                                                 \
      const int co_ = ((s * 2 + h) ^ c8) * 8;                                     \
      _Pragma("unroll")                                                           \
      for (int a = 0; a < 2; ++a) {                                               \
        bf16x8 kf_ = *(const bf16x8*)&(LCUR)[(a * 32 + lam) * 128 + co_];         \
        ACCP[a] = __builtin_amdgcn_mfma_f32_32x32x16_bf16(kf_, qf[s], ACCP[a], 0, 0, 0); \
      }                                                                           \
    }                                                                             \
  } while (0)

  // -------- pass 1: row sums only --------
  float lsum = 0.f;
  STAGEK(0, 0);
  int cur = 0;
  for (int kt = 0; kt < nkt; ++kt) {
    __syncthreads();
    if (kt + 1 < nkt) STAGEK(cur ^ 1, kt + 1);
    const short* lcur = (const short*)lK[cur];
    f32x16 accp[2] = {};
    QKT2(accp, lcur);
    const int kbase = kt * 64 - qb * 128;      // mask: kbase+kloc > qloc -> 0
#pragma unroll
    for (int a = 0; a < 2; ++a)
#pragma unroll
      for (int r = 0; r < 16; ++r) {
        int kloc = a * 32 + (r & 3) + 8 * (r >> 2) + 4 * h;
        float s = fminf(accp[a][r] * SCALEF, 60.f);
        float p = __expf(s);
        if (kbase + kloc > qloc) p = 0.f;
        lsum += p;
      }
    cur ^= 1;
  }
  lsum += __shfl_xor(lsum, 32);                // lanes l, l^32 share q
  const float invl = 1.f / lsum;

  // -------- pass 2: normalized P write + PV from LDS V --------
  __syncthreads();                             // all pass-1 lK reads done
  STAGEK(0, 0);
  cur = 0;
  f32x16 acco[4] = {};
  for (int kt = 0; kt < nkt; ++kt) {
    __syncthreads();                           // A: K[kt] landed, lV free
    STAGEV(kt);                                // flies under QK^T
    const short* lcur = (const short*)lK[cur];
    f32x16 accp[2] = {};
    QKT2(accp, lcur);
    __syncthreads();                           // B: V[kt] landed (K-stage NOT pending)
    if (kt + 1 < nkt) STAGEK(cur ^ 1, kt + 1); // drains at next A, under pn+stores+PV
    const int kbase = kt * 64 - qb * 128;
    float* prow = Pb + (long long)qloc * Sn + kt * 64 + 4 * h;
#pragma unroll
    for (int a = 0; a < 2; ++a) {
      float pn[16];
#pragma unroll
      for (int r = 0; r < 16; ++r) {
        int kloc = a * 32 + (r & 3) + 8 * (r >> 2) + 4 * h;
        float s = fminf(accp[a][r] * SCALEF, 60.f);
        float p = __expf(s) * invl;
        if (kbase + kloc > qloc) p = 0.f;
        pn[r] = p;
      }
      // normalized P store (regular cached stores: L2 ack hides under MFMA)
#pragma unroll
      for (int T = 0; T < 4; ++T) {
        f4v v = { pn[4 * T], pn[4 * T + 1], pn[4 * T + 2], pn[4 * T + 3] };
        *(f4v*)(prow + a * 32 + 8 * T) = v;
      }
      // PV: build A-frags for k-chunks c = 2a, 2a+1 via xor-32 exchange
#pragma unroll
      for (int ci = 0; ci < 2; ++ci) {
        const int ro = ci * 8;
        float r0 = __shfl_xor(h ? pn[ro + 0] : pn[ro + 4], 32);
        float r1 = __shfl_xor(h ? pn[ro + 1] : pn[ro + 5], 32);
        float r2 = __shfl_xor(h ? pn[ro + 2] : pn[ro + 6], 32);
        float r3 = __shfl_xor(h ? pn[ro + 3] : pn[ro + 7], 32);
        float t0 = h ? r0 : pn[ro + 0];
        float t1 = h ? r1 : pn[ro + 1];
        float t2 = h ? r2 : pn[ro + 2];
        float t3 = h ? r3 : pn[ro + 3];
        float t4 = h ? pn[ro + 4] : r0;
        float t5 = h ? pn[ro + 5] : r1;
        float t6 = h ? pn[ro + 6] : r2;
        float t7 = h ? pn[ro + 7] : r3;
        bf16x8 pf = { f2bf(t0), f2bf(t1), f2bf(t2), f2bf(t3),
                      f2bf(t4), f2bf(t5), f2bf(t6), f2bf(t7) };
        const int c = a * 2 + ci;
#pragma unroll
        for (int f = 0; f < 4; ++f) {
          bf16x8 vf = *(const bf16x8*)&lV[(f * 32 + lam) * 64 + ((c * 2 + h) ^ v8) * 8];
          acco[f] = __builtin_amdgcn_mfma_f32_32x32x16_bf16(pf, vf, acco[f], 0, 0, 0);
        }
      }
    }
    cur ^= 1;
  }
#undef QKT2
#undef STAGEV
#undef STAGEK

  // attn epilogue: O[q = w*32 + (r&3)+8(r>>2)+4h][d = f*32+lam], normalized
#pragma unroll
  for (int f = 0; f < 4; ++f)
#pragma unroll
    for (int r = 0; r < 16; ++r) {
      int qv = (r & 3) + 8 * (r >> 2) + 4 * h;
      long long q = (long long)qb * 128 + w * 32 + qv;
      attn[((long long)(b * Sn) + q) * Hn + hh * HDn + f * 32 + lam] = f2bf(acco[f][r]);
    }

  // inline upper-triangle zeros for this block's 128 rows
  {
    const int r0 = tid >> 3;
    const int c0 = tid & 7;
    f4v z = {0.f, 0.f, 0.f, 0.f};
    for (int ct = qb + 1; ct < 16; ++ct) {
      float* base = Pb + (long long)ct * 128;
#pragma unroll
      for (int rr = 0; rr < 128; rr += 32) {
        f4v* rowp = (f4v*)(base + (long long)(r0 + rr) * Sn);
#pragma unroll
        for (int c = 0; c < 4; ++c) __builtin_nontemporal_store(z, &rowp[c0 + c * 8]);
      }
    }
  }
}

// ---- workspace layout (bytes) -----------------------------------------
// hs_bf16   @ 0          (29,360,128)  -- reused later as attn_bf16
// wqkv_bf16 @ 29,360,128 (33,030,144)  -- reused later as q_bf16
// wo_bf16   @ 62,390,272 (25,690,112)
// bias_qkv  @ 88,080,384 (18,432)
// qkv_f32   @ 88,098,816 (75,497,472)
// k_bf16    @163,596,288 ( 4,194,304)
// vT_bf16   @167,790,592 ( 4,194,304)   total = 171,984,896 B

extern "C" void kernel_launch(void* const* d_in, const int* in_sizes, int n_in,
                              void* d_out, int out_size, void* d_ws, size_t ws_size,
                              hipStream_t stream) {
  const float* hs   = (const float*)d_in[0];
  const float* cosb = (const float*)d_in[1];
  const float* sinb = (const float*)d_in[2];
  // d_in[3] attention_mask: exact causal tril 0/-1e9, applied analytically
  const float* Wq = (const float*)d_in[4];
  const float* bq = (const float*)d_in[5];
  const float* Wk = (const float*)d_in[6];
  const float* bk = (const float*)d_in[7];
  const float* Wv = (const float*)d_in[8];
  const float* bv = (const float*)d_in[9];
  const float* Wo = (const float*)d_in[10];
  float* out   = (float*)d_out;
  float* probs = out + NOUT;
  char* ws = (char*)d_ws;
  short* hs_bf   = (short*)(ws + 0);
  short* attn_bf = hs_bf;                      // alias: hs dead after QKV GEMM
  short* wqkv_bf = (short*)(ws + 29360128LL);
  short* q_bf    = wqkv_bf;                    // alias: wqkv dead after QKV GEMM
  short* wo_bf   = (short*)(ws + 62390272LL);
  float* bias_qkv= (float*)(ws + 88080384LL);
  float* qkv     = (float*)(ws + 88098816LL);
  short* k_bf    = (short*)(ws + 163596288LL);
  short* vt_bf   = (short*)(ws + 167790592LL);

  cast_bf16<<<2048, 256, 0, stream>>>(hs, hs_bf, 3670016LL);
  cast_bf16<<<2048, 256, 0, stream>>>(Wq, wqkv_bf, 3211264LL);
  cast_bf16<<<512, 256, 0, stream>>>(Wk, wqkv_bf + 12845056LL, 458752LL);
  cast_bf16<<<512, 256, 0, stream>>>(Wv, wqkv_bf + 14680064LL, 458752LL);
  cast_bf16<<<2048, 256, 0, stream>>>(Wo, wo_bf, 3211264LL);
  concat_bias<<<18, 256, 0, stream>>>(bq, bk, bv, bias_qkv);

  // fused QKV projection: persistent grid, BK=64 swizzled core
  gemm_persist<<<768, 256, 0, stream>>>(hs_bf, wqkv_bf, qkv, bias_qkv, 3584, 4608, 36, 1152);

  rope_qk<<<4096, 256, 0, stream>>>(qkv, cosb, sinb, q_bf, k_bf);
  vtrans<<<dim3(64, 4, 8), dim3(32, 8), 0, stream>>>(qkv, vt_bf);

  // fully-fused attention (normalized P + attn + inline upper zeros)
  fused_attn6<<<dim3(16, 56), 256, 0, stream>>>(q_bf, k_bf, vt_bf, probs, attn_bf);

  // out = attn @ Wo^T: persistent grid, BK=64 swizzled core
  gemm_persist<<<768, 256, 0, stream>>>(attn_bf, wo_bf, out, nullptr, 3584, 3584, 28, 896);
}